// Round 2
// baseline (350.352 us; speedup 1.0000x reference)
//
#include <hip/hip_runtime.h>
#include <math.h>

// Problem constants (fixed by the reference)
#define BATCH 65536
#define DIM 128
#define NBAS 6
#define OUTW 896              // DIM*NBAS + DIM
#define ROWS 64               // rows per block tile
#define LSTR 132              // LDS row stride in floats: 128 + 4 pad (keeps 16B align)

// ---------------------------------------------------------------------------
// Kernel 1: S = sigmoid(W), 128x128 into workspace.
// ---------------------------------------------------------------------------
__global__ __launch_bounds__(256) void sigmoid_k(const float* __restrict__ W,
                                                 float* __restrict__ S) {
    int t = blockIdx.x * 256 + threadIdx.x;
    float w = W[t];
    S[t] = 1.0f / (1.0f + expf(-w));
}

// ---------------------------------------------------------------------------
// Uniform cubic B-spline closed form. knots = linspace(-1,1,10), h = 2/9.
// At x in cell c (= floor((x+1)*4.5)), the only nonzero basis functions are
// j = c-3..c (intersected with [0,5]); their values are the cardinal weights
//   w0=(1-u)^3/6  w1=(3u^3-6u^2+4)/6  w2=(-3u^3+3u^2+3u+1)/6  w3=u^3/6
// with u = frac((x+1)*4.5). Algebraically identical to the reference's
// Cox-de Boor recursion on this knot vector (all retained basis functions are
// pure translates of the cardinal spline; boundary ones are simply dropped).
// ---------------------------------------------------------------------------
__device__ __forceinline__ void wts(float x, int& cell,
                                    float& w0, float& w1, float& w2, float& w3) {
    float xc = fminf(fmaxf(x, -1.0f), 1.0f - 1e-6f);
    float t = (xc + 1.0f) * 4.5f;
    float cf = floorf(t);
    cell = (int)cf;
    float u = t - cf;
    float v = 1.0f - u;
    float u2 = u * u;
    float u3 = u2 * u;
    const float s6 = 1.0f / 6.0f;
    w0 = v * v * v * s6;
    w1 = (3.0f * u3 - 6.0f * u2 + 4.0f) * s6;
    w2 = (-3.0f * u3 + 3.0f * u2 + 3.0f * u + 1.0f) * s6;
    w3 = u3 * s6;
}

// B_{j,3}(x) given the cell and weights: nonzero iff c-3 <= j <= c.
__device__ __forceinline__ float bval(int j, int cell,
                                      float w0, float w1, float w2, float w3) {
    int idx = j - cell + 3;        // 0..3 -> w0..w3, else 0
    float r = 0.0f;
    r = (idx == 0) ? w0 : r;
    r = (idx == 1) ? w1 : r;
    r = (idx == 2) ? w2 : r;
    r = (idx == 3) ? w3 : r;
    return r;
}

// ---------------------------------------------------------------------------
// Main fused kernel. One block = one 64-row tile (1024 blocks, 4/CU).
// A0: coalesced x load -> LDS [r][i] (conflict-free b128 writes).
// A1: basis with PERFECTLY COALESCED stores: lane l of a wave writes output
//     float4 index 64q+l of one row (1 KB contiguous per store instruction).
//     f = 256q+4l is even -> j0 = f%6 in {0,2,4}; lane needs weights of
//     feature i0=f/6 and (only when j0==4) feature i0+1.
// B:  64x128 interaction GEMM vs S (L2-resident); x^2 computed on the fly
//     from broadcast LDS reads; 8 rows x 4 cols per thread.
// ---------------------------------------------------------------------------
__global__ __launch_bounds__(256, 4) void kan_main(const float* __restrict__ X,
                                                   const float* __restrict__ S,
                                                   float* __restrict__ out) {
    __shared__ __align__(16) float xrow[ROWS * LSTR];   // raw x, [r][i], 33.8 KB

    const int tid = threadIdx.x;
    const int row0 = blockIdx.x * ROWS;

    // ---------------- A0: stage x tile ----------------
    const float4* X4 = (const float4*)(X + (size_t)row0 * DIM);
#pragma unroll
    for (int k = 0; k < 8; ++k) {
        int e4 = k * 256 + tid;          // float4 index in tile, 0..2047
        int r = e4 >> 5;                 // 32 float4s per row
        int i = (e4 & 31) * 4;
        float4 xv = X4[e4];
        *(float4*)&xrow[r * LSTR + i] = xv;   // lanes -> consecutive banks, free
    }
    __syncthreads();

    // ---------------- A1: basis, coalesced stores ----------------
    const int lane = tid & 63;
    const int wv = tid >> 6;
#pragma unroll 4
    for (int jj = 0; jj < 48; ++jj) {
        int p = jj * 4 + wv;             // (row, q) pair index, 0..191
        int row = p / 3;                 // compile-time const divisor -> mulhi
        int q = p - row * 3;
        int f = 256 * q + 4 * lane;      // first output float, even
        int i0 = f / 6;
        int j0 = f - 6 * i0;             // in {0,2,4}

        float x0 = xrow[row * LSTR + i0];
        float x1 = xrow[row * LSTR + i0 + 1];   // i0+1 <= 128 < LSTR, in-bounds

        int c0, c1;
        float a0, a1, a2, a3, b0, b1, b2, b3;
        wts(x0, c0, a0, a1, a2, a3);
        wts(x1, c1, b0, b1, b2, b3);

        bool hi = (j0 == 4);
        float4 o;
        o.x = bval(j0 + 0, c0, a0, a1, a2, a3);
        o.y = bval(j0 + 1, c0, a0, a1, a2, a3);
        o.z = hi ? bval(0, c1, b0, b1, b2, b3) : bval(j0 + 2, c0, a0, a1, a2, a3);
        o.w = hi ? bval(1, c1, b0, b1, b2, b3) : bval(j0 + 3, c0, a0, a1, a2, a3);

        *(float4*)(out + (size_t)(row0 + row) * OUTW + f) = o;
    }

    // ---------------- B: interaction GEMM ----------------
    const int c = tid & 31;              // cols 4c..4c+3
    const int rg = tid >> 5;             // rows rg*8..rg*8+7
    const int r0 = rg * 8;

    float acc[8][4];
#pragma unroll
    for (int rr = 0; rr < 8; ++rr)
#pragma unroll
        for (int m = 0; m < 4; ++m) acc[rr][m] = 0.0f;

    const float4* S4 = (const float4*)S;
#pragma unroll 2
    for (int ib = 0; ib < 32; ++ib) {
        int i = ib * 4;
        float4 s0 = S4[(i + 0) * 32 + c];          // 512 B contiguous per wave
        float4 s1 = S4[(i + 1) * 32 + c];
        float4 s2 = S4[(i + 2) * 32 + c];
        float4 s3 = S4[(i + 3) * 32 + c];
#pragma unroll
        for (int rr = 0; rr < 8; ++rr) {
            float4 xv = *(const float4*)&xrow[(r0 + rr) * LSTR + i];  // broadcast
            float q0 = xv.x * xv.x;
            float q1 = xv.y * xv.y;
            float q2 = xv.z * xv.z;
            float q3 = xv.w * xv.w;
            acc[rr][0] = fmaf(q0, s0.x, acc[rr][0]);
            acc[rr][1] = fmaf(q0, s0.y, acc[rr][1]);
            acc[rr][2] = fmaf(q0, s0.z, acc[rr][2]);
            acc[rr][3] = fmaf(q0, s0.w, acc[rr][3]);
            acc[rr][0] = fmaf(q1, s1.x, acc[rr][0]);
            acc[rr][1] = fmaf(q1, s1.y, acc[rr][1]);
            acc[rr][2] = fmaf(q1, s1.z, acc[rr][2]);
            acc[rr][3] = fmaf(q1, s1.w, acc[rr][3]);
            acc[rr][0] = fmaf(q2, s2.x, acc[rr][0]);
            acc[rr][1] = fmaf(q2, s2.y, acc[rr][1]);
            acc[rr][2] = fmaf(q2, s2.z, acc[rr][2]);
            acc[rr][3] = fmaf(q2, s2.w, acc[rr][3]);
            acc[rr][0] = fmaf(q3, s3.x, acc[rr][0]);
            acc[rr][1] = fmaf(q3, s3.y, acc[rr][1]);
            acc[rr][2] = fmaf(q3, s3.z, acc[rr][2]);
            acc[rr][3] = fmaf(q3, s3.w, acc[rr][3]);
        }
    }

#pragma unroll
    for (int rr = 0; rr < 8; ++rr) {
        float4* o = (float4*)(out + (size_t)(row0 + r0 + rr) * OUTW + DIM * NBAS + 4 * c);
        *o = make_float4(acc[rr][0], acc[rr][1], acc[rr][2], acc[rr][3]);
    }
}

// ---------------------------------------------------------------------------
extern "C" void kernel_launch(void* const* d_in, const int* in_sizes, int n_in,
                              void* d_out, int out_size, void* d_ws, size_t ws_size,
                              hipStream_t stream) {
    const float* X = (const float*)d_in[0];
    const float* W = (const float*)d_in[1];
    float* out = (float*)d_out;
    float* S = (float*)d_ws;   // 64 KB scratch for sigmoid(W)

    sigmoid_k<<<(DIM * DIM) / 256, 256, 0, stream>>>(W, S);
    kan_main<<<BATCH / ROWS, 256, 0, stream>>>(X, S, out);
}

// Round 3
// 349.005 us; speedup vs baseline: 1.0039x; 1.0039x over previous
//
#include <hip/hip_runtime.h>
#include <math.h>

// Problem constants (fixed by the reference)
#define BATCH 65536
#define DIM 128
#define NBAS 6
#define OUTW 896              // DIM*NBAS + DIM
#define ROWS 64               // rows per block tile
#define LSTR 132              // LDS row stride in floats: 128 + 4 pad (16B-aligned rows)

// ---------------------------------------------------------------------------
// Kernel 1: S = sigmoid(W), 128x128 into workspace.
// ---------------------------------------------------------------------------
__global__ __launch_bounds__(256) void sigmoid_k(const float* __restrict__ W,
                                                 float* __restrict__ S) {
    int t = blockIdx.x * 256 + threadIdx.x;
    float w = W[t];
    S[t] = 1.0f / (1.0f + expf(-w));
}

// ---------------------------------------------------------------------------
// Uniform cubic B-spline closed form. knots = linspace(-1,1,10), h = 2/9.
// At x in cell c = floor((x+1)*4.5), nonzero basis j = c-3..c (clipped to
// [0,5]) with cardinal weights
//   w0=(1-u)^3/6  w1=(3u^3-6u^2+4)/6  w2=(-3u^3+3u^2+3u+1)/6  w3=u^3/6,
// u = frac((x+1)*4.5). Algebraically identical to the reference's Cox-de Boor
// recursion on this knot vector (retained basis functions are translates of
// the cardinal spline; boundary ones are dropped).
// ---------------------------------------------------------------------------
__device__ __forceinline__ void wts(float x, int& cell,
                                    float& w0, float& w1, float& w2, float& w3) {
    float xc = fminf(fmaxf(x, -1.0f), 1.0f - 1e-6f);
    float t = (xc + 1.0f) * 4.5f;
    float cf = floorf(t);
    cell = (int)cf;
    float u = t - cf;
    float v = 1.0f - u;
    float u2 = u * u;
    float u3 = u2 * u;
    const float s6 = 1.0f / 6.0f;
    w0 = v * v * v * s6;
    w1 = (3.0f * u3 - 6.0f * u2 + 4.0f) * s6;
    w2 = (-3.0f * u3 + 3.0f * u2 + 3.0f * u + 1.0f) * s6;
    w3 = u3 * s6;
}

// B_{j,3}(x): w[j-cell+3] if that index is in 0..3, else 0.
__device__ __forceinline__ float bval(int j, int cell,
                                      float w0, float w1, float w2, float w3) {
    int idx = j - cell + 3;
    float r = 0.0f;
    r = (idx == 0) ? w0 : r;
    r = (idx == 1) ? w1 : r;
    r = (idx == 2) ? w2 : r;
    r = (idx == 3) ? w3 : r;
    return r;
}

// ---------------------------------------------------------------------------
// Main fused kernel. One block = one 64-row tile (1024 blocks, 4/CU).
// A0: coalesced x load -> LDS [r][i] (conflict-free b128 writes).
// A1: basis with coalesced stores; q-outer/row-inner so the f/6 index math
//     (magic-mul div) is hoisted to 3x per thread instead of 48x.
// B : 64x128 interaction GEMM vs S (L2-resident), x^2 on the fly from
//     broadcast LDS reads; 8 rows x 4 cols per thread.
// ---------------------------------------------------------------------------
__global__ __launch_bounds__(256, 4) void kan_main(const float* __restrict__ X,
                                                   const float* __restrict__ S,
                                                   float* __restrict__ out) {
    __shared__ __align__(16) float xrow[ROWS * LSTR];   // raw x, [r][i], 33.8 KB

    const int tid = threadIdx.x;
    const int row0 = blockIdx.x * ROWS;

    // ---------------- A0: stage x tile ----------------
    const float4* X4 = (const float4*)(X + (size_t)row0 * DIM);
#pragma unroll
    for (int k = 0; k < 8; ++k) {
        int e4 = k * 256 + tid;          // float4 index in tile, 0..2047
        int r = e4 >> 5;                 // 32 float4s per row
        int i = (e4 & 31) * 4;
        float4 xv = X4[e4];
        *(float4*)&xrow[r * LSTR + i] = xv;   // lanes -> consecutive banks, free
    }
    __syncthreads();

    // ---------------- A1: basis, coalesced 1 KB wave stores ----------------
    // Wave wv handles rows {wv, wv+4, ..., wv+60}; lane l writes output
    // float4 index 64q+l of each row (f = 256q+4l, even -> j0 in {0,2,4}).
    const int lane = tid & 63;
    const int wv = tid >> 6;
#pragma unroll
    for (int q = 0; q < 3; ++q) {
        const int f = 256 * q + 4 * lane;     // first output float (even)
        const int i0 = f / 6;                 // hoisted: 3 divisions per thread
        const int j0 = f - 6 * i0;            // in {0,2,4}
        const bool hi = (j0 == 4);

        const float* xp = &xrow[wv * LSTR + i0];
        float* op = out + (size_t)(row0 + wv) * OUTW + f;

#pragma unroll 4
        for (int rr = 0; rr < 16; ++rr) {
            float x0 = xp[0];
            float x1 = xp[1];                 // i0+1 <= 128 < LSTR, in-bounds
            xp += 4 * LSTR;

            int c0, c1;
            float a0, a1, a2, a3, b0, b1, b2, b3;
            wts(x0, c0, a0, a1, a2, a3);
            wts(x1, c1, b0, b1, b2, b3);

            float4 o;
            o.x = bval(j0 + 0, c0, a0, a1, a2, a3);
            o.y = bval(j0 + 1, c0, a0, a1, a2, a3);
            o.z = hi ? bval(0, c1, b0, b1, b2, b3) : bval(j0 + 2, c0, a0, a1, a2, a3);
            o.w = hi ? bval(1, c1, b0, b1, b2, b3) : bval(j0 + 3, c0, a0, a1, a2, a3);

            *(float4*)op = o;
            op += (size_t)4 * OUTW;
        }
    }

    // ---------------- B: interaction GEMM ----------------
    const int c = tid & 31;              // cols 4c..4c+3
    const int rg = tid >> 5;             // rows rg*8..rg*8+7
    const int r0 = rg * 8;

    float acc[8][4];
#pragma unroll
    for (int rr = 0; rr < 8; ++rr)
#pragma unroll
        for (int m = 0; m < 4; ++m) acc[rr][m] = 0.0f;

    const float4* S4 = (const float4*)S;
#pragma unroll 2
    for (int ib = 0; ib < 32; ++ib) {
        int i = ib * 4;
        float4 s0 = S4[(i + 0) * 32 + c];          // 512 B contiguous per half-wave
        float4 s1 = S4[(i + 1) * 32 + c];
        float4 s2 = S4[(i + 2) * 32 + c];
        float4 s3 = S4[(i + 3) * 32 + c];
#pragma unroll
        for (int rr = 0; rr < 8; ++rr) {
            float4 xv = *(const float4*)&xrow[(r0 + rr) * LSTR + i];  // broadcast
            float q0 = xv.x * xv.x;
            float q1 = xv.y * xv.y;
            float q2 = xv.z * xv.z;
            float q3 = xv.w * xv.w;
            acc[rr][0] = fmaf(q0, s0.x, acc[rr][0]);
            acc[rr][1] = fmaf(q0, s0.y, acc[rr][1]);
            acc[rr][2] = fmaf(q0, s0.z, acc[rr][2]);
            acc[rr][3] = fmaf(q0, s0.w, acc[rr][3]);
            acc[rr][0] = fmaf(q1, s1.x, acc[rr][0]);
            acc[rr][1] = fmaf(q1, s1.y, acc[rr][1]);
            acc[rr][2] = fmaf(q1, s1.z, acc[rr][2]);
            acc[rr][3] = fmaf(q1, s1.w, acc[rr][3]);
            acc[rr][0] = fmaf(q2, s2.x, acc[rr][0]);
            acc[rr][1] = fmaf(q2, s2.y, acc[rr][1]);
            acc[rr][2] = fmaf(q2, s2.z, acc[rr][2]);
            acc[rr][3] = fmaf(q2, s2.w, acc[rr][3]);
            acc[rr][0] = fmaf(q3, s3.x, acc[rr][0]);
            acc[rr][1] = fmaf(q3, s3.y, acc[rr][1]);
            acc[rr][2] = fmaf(q3, s3.z, acc[rr][2]);
            acc[rr][3] = fmaf(q3, s3.w, acc[rr][3]);
        }
    }

#pragma unroll
    for (int rr = 0; rr < 8; ++rr) {
        float4* o = (float4*)(out + (size_t)(row0 + r0 + rr) * OUTW + DIM * NBAS + 4 * c);
        *o = make_float4(acc[rr][0], acc[rr][1], acc[rr][2], acc[rr][3]);
    }
}

// ---------------------------------------------------------------------------
extern "C" void kernel_launch(void* const* d_in, const int* in_sizes, int n_in,
                              void* d_out, int out_size, void* d_ws, size_t ws_size,
                              hipStream_t stream) {
    const float* X = (const float*)d_in[0];
    const float* W = (const float*)d_in[1];
    float* out = (float*)d_out;
    float* S = (float*)d_ws;   // 64 KB scratch for sigmoid(W)

    sigmoid_k<<<(DIM * DIM) / 256, 256, 0, stream>>>(W, S);
    kan_main<<<BATCH / ROWS, 256, 0, stream>>>(X, S, out);
}